// Round 3
// baseline (289.070 us; speedup 1.0000x reference)
//
#include <hip/hip_runtime.h>

// Dynamic per-pixel 5x5 conv (replicate pad) + leaky_relu(0.2).
// x: (N,C,H,W) f32; kernel: (N, C*25, H, W) f32; out: (N,C,H,W) f32.
//
// Round 3: stream-locality experiment. One 1024-thread block = 16 consecutive
// rows of one (n,c) image, so each block reads 25 contiguous 16 KB chunks of
// the kernel tensor (vs 25 x 4 KB for 256-thread blocks). Cuts concurrent
// DRAM streams per CU 4x (100 -> 25). Wave = one row; 8-wide input window via
// lane shuffles as in round 2.

constexpr int N = 4, C = 8, H = 256, W = 256, K = 5, PAD = 2;
constexpr int HW = H * W;
constexpr float NEG_SLOPE = 0.2f;

__global__ __launch_bounds__(1024, 4) void dyn_conv5x5(
    const float* __restrict__ x,
    const float* __restrict__ kern,
    float* __restrict__ out) {
    // block b: nc = b>>4, row-group g = b&15. wave = one row.
    int b    = blockIdx.x;
    int nc   = b >> 4;
    int g    = b & 15;
    int wave = threadIdx.x >> 6;
    int lane = threadIdx.x & 63;
    int y    = (g << 4) + wave;
    int x0   = lane << 2;

    const float* kbase = kern + (size_t)(25 * nc) * HW + y * W + x0;
    const float* xbase = x + (size_t)nc * HW;

    float acc0 = 0.f, acc1 = 0.f, acc2 = 0.f, acc3 = 0.f;

    #pragma unroll
    for (int k1 = 0; k1 < K; ++k1) {
        int yy = y + k1 - PAD;
        yy = yy < 0 ? 0 : (yy > H - 1 ? H - 1 : yy);

        // Own aligned float4: x[yy][x0 .. x0+3]
        const float4 bv = *(const float4*)(xbase + yy * W + x0);

        // Window x[yy][x0-2 .. x0+5] from neighbor lanes.
        float w0 = __shfl_up(bv.z, 1);
        float w1 = __shfl_up(bv.w, 1);
        float w6 = __shfl_down(bv.x, 1);
        float w7 = __shfl_down(bv.y, 1);
        w0 = (lane == 0)  ? bv.x : w0;
        w1 = (lane == 0)  ? bv.x : w1;
        w6 = (lane == 63) ? bv.w : w6;
        w7 = (lane == 63) ? bv.w : w7;

        const float w8[8] = {w0, w1, bv.x, bv.y, bv.z, bv.w, w6, w7};

        #pragma unroll
        for (int k2 = 0; k2 < K; ++k2) {
            const float4 kv =
                *(const float4*)(kbase + (size_t)(k1 * K + k2) * HW);
            acc0 = fmaf(kv.x, w8[k2 + 0], acc0);
            acc1 = fmaf(kv.y, w8[k2 + 1], acc1);
            acc2 = fmaf(kv.z, w8[k2 + 2], acc2);
            acc3 = fmaf(kv.w, w8[k2 + 3], acc3);
        }
    }

    float4 o;
    o.x = acc0 >= 0.f ? acc0 : NEG_SLOPE * acc0;
    o.y = acc1 >= 0.f ? acc1 : NEG_SLOPE * acc1;
    o.z = acc2 >= 0.f ? acc2 : NEG_SLOPE * acc2;
    o.w = acc3 >= 0.f ? acc3 : NEG_SLOPE * acc3;
    *(float4*)(out + (size_t)nc * HW + y * W + x0) = o;
}

extern "C" void kernel_launch(void* const* d_in, const int* in_sizes, int n_in,
                              void* d_out, int out_size, void* d_ws, size_t ws_size,
                              hipStream_t stream) {
    const float* x    = (const float*)d_in[0];
    const float* kern = (const float*)d_in[1];
    float* out        = (float*)d_out;

    constexpr int block = 1024;
    constexpr int grid = N * C * (H / 16);  // 32 nc * 16 row-groups = 512
    dyn_conv5x5<<<grid, block, 0, stream>>>(x, kern, out);
}